// Round 17
// baseline (96.395 us; speedup 1.0000x reference)
//
#include <hip/hip_runtime.h>
#include <math.h>

namespace {

constexpr int CCH = 128;   // classes
constexpr int BLANK = 1;
constexpr int CH = 32;     // scan steps per chunk
constexpr int NSLOT = 4;   // LDS g-ring slots (128 KB)
constexpr int NPROD = 4;   // producer waves per block
constexpr int MAXF = 128;  // ready-flag capacity (nit <= 64)
constexpr int DSTR = 524;  // f64 stride per (b,dir) result record

__device__ __forceinline__ int imax(int a, int b) { return a > b ? a : b; }
__device__ __forceinline__ int imin(int a, int b) { return a < b ? a : b; }

// lane i <- lane i-1 (lane 0 <- 0.0), pure VALU (DPP wave_shr:1)
__device__ __forceinline__ double dpp_shr1_f64(double x) {
    int lo = __double2loint(x), hi = __double2hiint(x);
    lo = __builtin_amdgcn_update_dpp(0, lo, 0x138, 0xF, 0xF, true);
    hi = __builtin_amdgcn_update_dpp(0, hi, 0x138, 0xF, 0xF, true);
    return __hiloint2double(hi, lo);
}

// ---------------- fused pass: 4 producer waves + 1 consumer wave ------------
// BWD uses mirrored states sigma = 512 - s, making its step identical to FWD's.
template<int BWD>
__device__ __forceinline__ void scan_dir(const float* __restrict__ lp,
                                         const int* __restrict__ ilen,
                                         const int* __restrict__ tgt,
                                         const int* __restrict__ tlen,
                                         double* __restrict__ dout,
                                         int T, int B, int L, int b,
                                         float (*gring)[CH][256],
                                         int* __restrict__ ready,
                                         int* __restrict__ donec)
{
    const int tid  = threadIdx.x;
    const int lane = tid & 63;
    int Tb = ilen[b]; if (Tb < 1) Tb = 1; if (Tb > T) Tb = T;
    int U  = tlen[b]; if (U < 0) U = 0;   if (U > L) U = L;
    const int m  = imax(1, Tb >> 1);     // forward: t in [0,m-1]; backward: [m,Tb-1]
    const int te = Tb - 1;
    const int maxch = T / CH - 1;

    int nit, cL = 0, c0 = 0;
    if (!BWD) {
        nit = (m + CH - 1) / CH;
    } else if (m > te) {                 // Tb==1: no backward steps
        nit = 0;
    } else {
        cL = te / CH; c0 = m / CH; nit = cL - c0 + 1;
    }

    auto chunk_of = [&](int i) {
        const int c = BWD ? (cL - i) : i;
        return imin(imax(c, 0), maxch);
    };

    // ---- LDS flag init (all 5 waves) ----
    for (int x = tid; x < MAXF; x += 64 * (NPROD + 1)) ready[x] = 0;
    if (tid == 0) *donec = 0;
    __syncthreads();

    // =================== producer waves ===================
    if (tid >= 64) {
        const int p = (tid >> 6) - 1;    // 0..3
        const int4 l4 = *reinterpret_cast<const int4*>(tgt + (size_t)b * L + lane * 4);
        const int c4[4] = {l4.x, l4.y, l4.z, l4.w};
        int lab[4];
#pragma unroll
        for (int k = 0; k < 4; ++k)
            lab[k] = (lane * 4 + k < U) ? (c4[k] & 127) : BLANK;

        double sb = 0.0;
        for (int j = p; j < nit; j += NPROD) {
            if (j >= NSLOT) {            // wait: slot (j&3) free (chunk j-4 consumed)
                while (__hip_atomic_load(donec, __ATOMIC_ACQUIRE,
                                         __HIP_MEMORY_SCOPE_WORKGROUP) < j - (NSLOT - 1))
                    __builtin_amdgcn_s_sleep(1);
            }
            const int c = chunk_of(j);
            float* slot = &gring[j & (NSLOT - 1)][0][0];
            const float* rowp = lp + ((size_t)(c * CH) * B + b) * CCH;
#pragma unroll 4
            for (int r = 0; r < CH; ++r) {
                const float* rp = rowp + (size_t)r * B * CCH;
                const float lpbv = rp[BLANK];
                float4 g;
                g.x = __expf(rp[lab[0]] - lpbv);   // pos>=U -> expf(0)=1 exactly
                g.y = __expf(rp[lab[1]] - lpbv);
                g.z = __expf(rp[lab[2]] - lpbv);
                g.w = __expf(rp[lab[3]] - lpbv);
                *reinterpret_cast<float4*>(slot + r * 256 + lane * 4) = g;
                const int t = c * CH + r;
                const bool valid = BWD ? (t >= m && t <= te) : (t < m);
                if (valid) sb += (double)lpbv;     // uniform across lanes
            }
            __hip_atomic_store(&ready[j], 1, __ATOMIC_RELEASE,
                               __HIP_MEMORY_SCOPE_WORKGROUP);  // g-writes drained first
        }
        if (lane == 0) {
            double* o = dout + (size_t)(BWD ? B + b : b) * DSTR;
            o[517 + p] = sb;             // per-producer fixed-order partial sum
        }
        return;
    }

    // =================== consumer wave (proven math) ===================
    double skipm[4];
    if (!BWD) {
        const int4 l4 = *reinterpret_cast<const int4*>(tgt + (size_t)b * L + lane * 4);
        const int labs[4] = {l4.x, l4.y, l4.z, l4.w};
        const int prevlast = __shfl_up(labs[3], 1);
#pragma unroll
        for (int k = 0; k < 4; ++k) {
            const int pos = lane * 4 + k;
            const int e = (pos < U) ? labs[k] : BLANK;
            int ep = (k == 0) ? ((pos >= 1) ? prevlast : BLANK) : labs[k - 1];
            ep = (pos >= 1 && pos - 1 < U) ? ep : BLANK;
            skipm[k] = (e != BLANK && e != ep) ? 1.0 : 0.0;
        }
    } else {
        const int4 l4 = *reinterpret_cast<const int4*>(tgt + (size_t)b * L + (63 - lane) * 4);
        const int labs[4] = {l4.x, l4.y, l4.z, l4.w};     // pos (63-lane)*4 + 0..3
        const int prevfirst = __shfl_up(labs[0], 1);      // lane-1's first label
#pragma unroll
        for (int k = 0; k < 4; ++k) {
            const int pos = 255 - lane * 4 - k;
            const int mylab = labs[3 - k];
            const int nxt = (k == 0) ? prevfirst : labs[4 - k];
            skipm[k] = ((pos + 1) < U && nxt != mylab) ? 1.0 : 0.0;
        }
    }

    double a[8];
#pragma unroll
    for (int j = 0; j < 8; ++j) a[j] = 0.0;
    double a512 = 0.0;    // fwd: s=512 shadow (lane63); bwd: sigma=512 (s=0) shadow
    int logz = 0;

    float4 R[CH];
    const int rdlane = (BWD ? (63 - lane) : lane) * 4;

    auto poll = [&](int i) {
        while (__hip_atomic_load(&ready[i], __ATOMIC_ACQUIRE,
                                 __HIP_MEMORY_SCOPE_WORKGROUP) == 0)
            __builtin_amdgcn_s_sleep(1);
    };

    auto c_load = [&](int i) {
        const float* sp = &gring[i & (NSLOT - 1)][0][0] + rdlane;
#pragma unroll
        for (int r = 0; r < CH; ++r)
            R[r] = *reinterpret_cast<const float4*>(sp + r * 256);
    };

    auto step = [&](const float4 gf) {
        const double g0 = (double)gf.x, g1 = (double)gf.y,
                     g2 = (double)gf.z, g3 = (double)gf.w;
        const double am1 = dpp_shr1_f64(a[7]);   // state[base-1] (lane0 -> 0)
        a512 += a[7];                            // pre-update a[7]
        const double n0 = a[0] + am1;
        const double n1 = (a[1] + a[0] + skipm[0] * am1) * g0;
        const double n2 = a[2] + a[1];
        const double n3 = (a[3] + a[2] + skipm[1] * a[1]) * g1;
        const double n4 = a[4] + a[3];
        const double n5 = (a[5] + a[4] + skipm[2] * a[3]) * g2;
        const double n6 = a[6] + a[5];
        const double n7 = (a[7] + a[6] + skipm[3] * a[5]) * g3;
        a[0] = n0; a[1] = n1; a[2] = n2; a[3] = n3;
        a[4] = n4; a[5] = n5; a[6] = n6; a[7] = n7;
    };

    auto rescale = [&]() {
        double mx = fmax(fmax(fmax(a[0], a[1]), fmax(a[2], a[3])),
                         fmax(fmax(a[4], a[5]), fmax(a[6], a[7])));
        int v = __double2hiint(mx);              // nonneg doubles: hi-word order = fp order
        int t;
        t = __builtin_amdgcn_update_dpp(0, v, 0x111, 0xF, 0xF, true); v = imax(v, t);
        t = __builtin_amdgcn_update_dpp(0, v, 0x112, 0xF, 0xF, true); v = imax(v, t);
        t = __builtin_amdgcn_update_dpp(0, v, 0x114, 0xF, 0xF, true); v = imax(v, t);
        t = __builtin_amdgcn_update_dpp(0, v, 0x118, 0xF, 0xF, true); v = imax(v, t);
        const int m0 = __builtin_amdgcn_readlane(v, 15);
        const int m1 = __builtin_amdgcn_readlane(v, 31);
        const int m2 = __builtin_amdgcn_readlane(v, 47);
        const int m3 = __builtin_amdgcn_readlane(v, 63);
        const int mb = imax(imax(m0, m1), imax(m2, m3));
        const int e11 = (mb >> 20) & 0x7FF;
        if (e11 > 0) {
            const double sc = __hiloint2double((2046 - e11) << 20, 0);  // 2^(1023-e11)
#pragma unroll
            for (int j = 0; j < 8; ++j) a[j] *= sc;
            a512 *= sc;
            logz += e11 - 1023;
        }
    };

    auto gswap = [](float4 v) { return make_float4(v.w, v.z, v.y, v.x); };
    auto initB = [&](float4 Rr) {                // delta_{Tb-1}
        const float4 g = gswap(Rr);
        const float gv[4] = {g.x, g.y, g.z, g.w};
#pragma unroll
        for (int j = 0; j < 8; ++j) {
            const int sig = 8 * lane + j;
            if ((j & 1) == 0) a[j] = (sig == 512 - 2 * U) ? 1.0 : 0.0;
            else              a[j] = (sig == 513 - 2 * U) ? (double)gv[(j - 1) >> 1] : 0.0;
        }
        a512 = (U == 0) ? 1.0 : 0.0;
    };

    auto consume = [&](int c) {
        if (!BWD) {
            const int t0 = c * CH;
            if (c == 0) {
                if (lane == 0) { a[0] = 1.0; a[1] = (double)R[0].x; }   // alpha_0
#pragma unroll
                for (int r = 1; r < CH; ++r) if (r < m) step(R[r]);
            } else if (t0 + CH <= m) {
#pragma unroll
                for (int r = 0; r < CH; ++r) step(R[r]);                // fast path
            } else {
#pragma unroll
                for (int r = 0; r < CH; ++r) if (t0 + r < m) step(R[r]);
            }
        } else {
            const int t0 = c * CH;
            if (t0 >= m && t0 + CH - 1 < te) {
#pragma unroll
                for (int r = CH - 1; r >= 0; --r) step(gswap(R[r]));    // fast path
            } else {
#pragma unroll
                for (int r = CH - 1; r >= 0; --r) {
                    const int t = t0 + r;
                    if (t > te || t < m) continue;
                    if (t == te) initB(R[r]); else step(gswap(R[r]));
                }
            }
        }
    };

    if (nit > 0) { poll(0); c_load(0); }
    for (int i = 0; i < nit; ++i) {
        consume(chunk_of(i));
        __hip_atomic_store(donec, i + 1, __ATOMIC_RELEASE,
                           __HIP_MEMORY_SCOPE_WORKGROUP);   // slot (i&3) reusable
        if (i + 1 < nit) { poll(i + 1); c_load(i + 1); }
        rescale();                        // every 32 steps, exact pow-2 (bit-identical)
    }
    if (BWD && nit == 0) {                // Tb==1: virtual terminal indicator
#pragma unroll
        for (int j = 0; j < 8; ++j) {
            const int sig = 8 * lane + j;
            a[j] = (((j & 1) == 0) && sig == 512 - 2 * U) ? 1.0 : 0.0;
        }
        a512 = (U == 0) ? 1.0 : 0.0;
    }

    // ---- epilogue: write s-indexed state + meta ----
    double* o = dout + (size_t)(BWD ? B + b : b) * DSTR;
#pragma unroll
    for (int j = 0; j < 8; ++j) {
        const int idx = BWD ? (512 - (8 * lane + j)) : (8 * lane + j);
        o[idx] = a[j];
    }
    if (lane == 63) o[BWD ? 0 : 512] = a512;
    if (lane == 0) {
        o[513] = 0.0; o[514] = 0.0; o[515] = 0.0;    // zero pad (combine reads s+1,s+2)
        o[516] = (double)logz;
    }
}

__global__ __launch_bounds__(64 * (NPROD + 1), 1)
void ctc_scan2(const float* __restrict__ lp, const int* __restrict__ ilen,
               const int* __restrict__ tgt, const int* __restrict__ tlen,
               double* __restrict__ dout, int T, int B, int L)
{
    __shared__ float gring[NSLOT][CH][256];   // 128 KB g-value ring
    __shared__ int   ready[MAXF];
    __shared__ int   donec;
    const int bid = blockIdx.x;
    if (bid < B) scan_dir<0>(lp, ilen, tgt, tlen, dout, T, B, L, bid, gring, ready, &donec);
    else         scan_dir<1>(lp, ilen, tgt, tlen, dout, T, B, L, bid - B, gring, ready, &donec);
}

// ---------------- pass 2: combine fwd/bwd halves ----------------
__global__ __launch_bounds__(64)
void ctc_combine(const double* __restrict__ dout,
                 const int* __restrict__ tgt,
                 const int* __restrict__ tlen,
                 float* __restrict__ perb, int B, int L)
{
    const int b = blockIdx.x;
    const int lane = threadIdx.x;
    int U = tlen[b]; if (U < 0) U = 0; if (U > L) U = L;

    const double* af = dout + (size_t)b * DSTR;
    const double* db = dout + (size_t)(B + b) * DSTR;

    const int4 l4 = *reinterpret_cast<const int4*>(tgt + (size_t)b * L + lane * 4);
    const int labs[4] = {l4.x, l4.y, l4.z, l4.w};
    const int nextfirst = __shfl_down(labs[0], 1);   // pos 4*lane+4

    double dd[10];
#pragma unroll
    for (int i = 0; i < 10; ++i) dd[i] = db[8 * lane + i];   // max idx 513 (zero pad)
    double av[8];
#pragma unroll
    for (int j = 0; j < 8; ++j) av[j] = af[8 * lane + j];

    double p = 0.0;
#pragma unroll
    for (int j = 0; j < 8; ++j) {
        if ((j & 1) == 0) {
            p += av[j] * (dd[j] + dd[j + 1]);
        } else {
            const int k = (j - 1) >> 1;
            const int pos = 4 * lane + k;
            const int nxt = (k < 3) ? labs[k + 1] : nextfirst;
            const double sk = ((pos + 1) < U && nxt != labs[k]) ? 1.0 : 0.0;
            p += av[j] * (dd[j] + dd[j + 1] + sk * dd[j + 2]);
        }
    }
    if (lane == 63) p += af[512] * db[512];
#pragma unroll
    for (int off = 32; off >= 1; off >>= 1) p += __shfl_xor(p, off);

    if (lane == 0) {
        const double zF = af[516], sF = af[517] + af[518] + af[519] + af[520];
        const double zB = db[516], sB = db[517] + db[518] + db[519] + db[520];
        const double ll = log(p) + sF + sB + (zF + zB) * 0.6931471805599453;
        perb[b] = (float)(-ll);
    }
}

// ---------------- fallback: proven round-3 single-kernel path ----------------
constexpr int FCH = 8;
constexpr int ROWD = 128;

__global__ __launch_bounds__(64, 1)
void ctc_fwd(const float* __restrict__ lp,
             const int* __restrict__ ilen,
             const int* __restrict__ tgt,
             const int* __restrict__ tlen,
             float* __restrict__ perb,
             int T, int B, int L)
{
    const int b = blockIdx.x;
    const int lane = threadIdx.x;
    int Tb = ilen[b]; if (Tb < 1) Tb = 1; if (Tb > T) Tb = T;
    int U  = tlen[b]; if (U < 0) U = 0;   if (U > L) U = L;

    __shared__ double pbuf[2][FCH][ROWD];
    __shared__ double afin[2 * 256 + 2];

    const int4 lab4 = *reinterpret_cast<const int4*>(tgt + (size_t)b * L + lane * 4);
    const int labs[4] = {lab4.x, lab4.y, lab4.z, lab4.w};
    const int prevlast = __shfl_up(labs[3], 1);
    int ext[4];
    double skipm[4];
#pragma unroll
    for (int k = 0; k < 4; ++k) {
        const int pos = lane * 4 + k;
        ext[k] = (pos < U) ? labs[k] : BLANK;
        const int prev = (k == 0) ? ((pos >= 1) ? prevlast : BLANK) : labs[k - 1];
        const int eprev = (pos >= 1 && pos - 1 < U) ? prev : BLANK;
        skipm[k] = (ext[k] != BLANK && ext[k] != eprev) ? 1.0 : 0.0;
    }

    const float* base = lp + (size_t)b * CCH;
    const size_t rowstride = (size_t)B * CCH;

    float2 rA[FCH], rB[FCH];
    double sblank = 0.0;
    int logz = 0;
    double a[8];
    double a512 = 0.0;
    double G[FCH][4];

    auto issue = [&](float2* r, int chunk) {
#pragma unroll
        for (int i = 0; i < FCH; ++i) {
            int t = chunk * FCH + i;
            t = (t < T) ? t : (T - 1);
            r[i] = *reinterpret_cast<const float2*>(base + (size_t)t * rowstride + 2 * lane);
        }
    };

    auto stage = [&](const float2* r, int buf, int chunk) {
#pragma unroll
        for (int i = 0; i < FCH; ++i) {
            const float2 v = r[i];
            const float lpb = __int_as_float(
                __builtin_amdgcn_readfirstlane(__float_as_int(v.y)));
            const int t = chunk * FCH + i;
            if (t < Tb) sblank += (double)lpb;
            double2 p;
            p.x = (double)__expf(v.x - lpb);
            p.y = (double)__expf(v.y - lpb);
            *reinterpret_cast<double2*>(&pbuf[buf][i][2 * lane]) = p;
        }
    };

    auto gather = [&](int buf) {
#pragma unroll
        for (int r = 0; r < FCH; ++r)
#pragma unroll
            for (int k = 0; k < 4; ++k)
                G[r][k] = pbuf[buf][r][ext[k]];
    };

    auto step = [&](const double* g) {
        const double am1 = dpp_shr1_f64(a[7]);
        a512 += a[7];
        const double n0 = a[0] + am1;
        const double n1 = (a[1] + a[0] + skipm[0] * am1) * g[0];
        const double n2 = a[2] + a[1];
        const double n3 = (a[3] + a[2] + skipm[1] * a[1]) * g[1];
        const double n4 = a[4] + a[3];
        const double n5 = (a[5] + a[4] + skipm[2] * a[3]) * g[2];
        const double n6 = a[6] + a[5];
        const double n7 = (a[7] + a[6] + skipm[3] * a[5]) * g[3];
        a[0] = n0; a[1] = n1; a[2] = n2; a[3] = n3;
        a[4] = n4; a[5] = n5; a[6] = n6; a[7] = n7;
    };

    auto rescale = [&]() {
        double m = fmax(fmax(fmax(a[0], a[1]), fmax(a[2], a[3])),
                        fmax(fmax(a[4], a[5]), fmax(a[6], a[7])));
        int v = __double2hiint(m);
        int t;
        t = __builtin_amdgcn_update_dpp(0, v, 0x111, 0xF, 0xF, true); v = imax(v, t);
        t = __builtin_amdgcn_update_dpp(0, v, 0x112, 0xF, 0xF, true); v = imax(v, t);
        t = __builtin_amdgcn_update_dpp(0, v, 0x114, 0xF, 0xF, true); v = imax(v, t);
        t = __builtin_amdgcn_update_dpp(0, v, 0x118, 0xF, 0xF, true); v = imax(v, t);
        const int m0 = __builtin_amdgcn_readlane(v, 15);
        const int m1 = __builtin_amdgcn_readlane(v, 31);
        const int m2 = __builtin_amdgcn_readlane(v, 47);
        const int m3 = __builtin_amdgcn_readlane(v, 63);
        const int mb = imax(imax(m0, m1), imax(m2, m3));
        const int e11 = (mb >> 20) & 0x7FF;
        if (e11 > 0) {
            const double sc = __hiloint2double((2046 - e11) << 20, 0);
#pragma unroll
            for (int j = 0; j < 8; ++j) a[j] *= sc;
            a512 *= sc;
            logz += e11 - 1023;
        }
    };

    issue(rA, 0);
    issue(rB, 1);
    stage(rA, 0, 0);
    issue(rA, 2);
#pragma unroll
    for (int j = 0; j < 8; ++j) a[j] = 0.0;

    const int nch = (Tb + FCH - 1) / FCH;

    for (int c = 0; c < nch; ++c) {
        const int buf = c & 1;
        gather(buf);
        if (c + 1 < nch) {
            if ((c + 1) & 1) { stage(rB, 1, c + 1); issue(rB, c + 3); }
            else             { stage(rA, 0, c + 1); issue(rA, c + 3); }
        }
        const int t0 = c * FCH;
        if (c == 0) {
            if (lane == 0) { a[0] = 1.0; a[1] = G[0][0]; }
#pragma unroll
            for (int r = 1; r < FCH; ++r) if (r < Tb) step(G[r]);
        } else if (t0 + FCH <= Tb) {
#pragma unroll
            for (int r = 0; r < FCH; ++r) step(G[r]);
        } else {
#pragma unroll
            for (int r = 0; r < FCH; ++r) if (t0 + r < Tb) step(G[r]);
        }
        if ((c & 1) || (c == nch - 1)) rescale();
    }

#pragma unroll
    for (int j = 0; j < 8; ++j) afin[lane * 8 + j] = a[j];
    if (lane == 63) afin[512] = a512;
    __syncthreads();
    if (lane == 0) {
        const int i1 = 2 * U;
        int i2 = 2 * U - 1; if (i2 < 0) i2 = 0;
        const double ssum = afin[i1] + afin[i2];
        const double ll = log(ssum) + sblank + (double)logz * 0.6931471805599453;
        perb[b] = (float)(-ll);
    }
}

__global__ void reduce_sum(const float* __restrict__ perb, float* __restrict__ out, int B)
{
    const int lane = threadIdx.x;
    double v = 0.0;
    for (int i = lane; i < B; i += 64) v += (double)perb[i];
#pragma unroll
    for (int off = 32; off >= 1; off >>= 1) v += __shfl_xor(v, off);
    if (lane == 0) out[0] = (float)v;
}

} // namespace

extern "C" void kernel_launch(void* const* d_in, const int* in_sizes, int n_in,
                              void* d_out, int out_size, void* d_ws, size_t ws_size,
                              hipStream_t stream)
{
    const float* lp  = (const float*)d_in[0];   // [T,B,C] log-softmax, f32
    const int* ilen  = (const int*)d_in[1];     // [B]
    const int* tgt   = (const int*)d_in[2];     // [B,L]
    const int* tlen  = (const int*)d_in[3];     // [B]

    const int B = in_sizes[1];
    const int L = in_sizes[2] / B;
    const int T = in_sizes[0] / (B * CCH);

    const size_t dbytes = (size_t)2 * B * DSTR * sizeof(double);
    const size_t need   = dbytes + (size_t)B * sizeof(float);

    if (ws_size >= need && L == 256 && (T % CH) == 0) {
        double* dout = (double*)d_ws;
        float*  perb = (float*)((char*)d_ws + dbytes);
        ctc_scan2<<<2 * B, 64 * (NPROD + 1), 0, stream>>>(lp, ilen, tgt, tlen, dout, T, B, L);
        ctc_combine<<<B, 64, 0, stream>>>(dout, tgt, tlen, perb, B, L);
        reduce_sum<<<1, 64, 0, stream>>>(perb, (float*)d_out, B);
    } else {
        float* perb = (float*)d_ws;
        ctc_fwd<<<B, 64, 0, stream>>>(lp, ilen, tgt, tlen, perb, T, B, L);
        reduce_sum<<<1, 64, 0, stream>>>(perb, (float*)d_out, B);
    }
}

// Round 18
// 73.727 us; speedup vs baseline: 1.3075x; 1.3075x over previous
//
#include <hip/hip_runtime.h>
#include <math.h>

namespace {

constexpr int CCH = 128;   // classes
constexpr int BLANK = 1;
constexpr int CH = 16;     // scan steps per chunk
constexpr int NSLOT = 8;   // LDS g-ring slots (128 KB)
constexpr int NPROD = 3;   // producer waves per block (4 waves total = 1/SIMD)
constexpr int MAXF = 128;  // ready-flag capacity (nit <= 64)
constexpr int DSTR = 524;  // f64 stride per (b,dir) result record

__device__ __forceinline__ int imax(int a, int b) { return a > b ? a : b; }
__device__ __forceinline__ int imin(int a, int b) { return a < b ? a : b; }

// lane i <- lane i-1 (lane 0 <- 0.0), pure VALU (DPP wave_shr:1)
__device__ __forceinline__ double dpp_shr1_f64(double x) {
    int lo = __double2loint(x), hi = __double2hiint(x);
    lo = __builtin_amdgcn_update_dpp(0, lo, 0x138, 0xF, 0xF, true);
    hi = __builtin_amdgcn_update_dpp(0, hi, 0x138, 0xF, 0xF, true);
    return __hiloint2double(hi, lo);
}

// ---------------- fused pass: 3 producer waves + 1 consumer wave ------------
// BWD uses mirrored states sigma = 512 - s, making its step identical to FWD's.
template<int BWD>
__device__ __forceinline__ void scan_dir(const float* __restrict__ lp,
                                         const int* __restrict__ ilen,
                                         const int* __restrict__ tgt,
                                         const int* __restrict__ tlen,
                                         double* __restrict__ dout,
                                         int T, int B, int L, int b,
                                         float (*gring)[CH][256],
                                         int* __restrict__ ready,
                                         int* __restrict__ donec)
{
    const int tid  = threadIdx.x;
    const int lane = tid & 63;
    int Tb = ilen[b]; if (Tb < 1) Tb = 1; if (Tb > T) Tb = T;
    int U  = tlen[b]; if (U < 0) U = 0;   if (U > L) U = L;
    const int m  = imax(1, Tb >> 1);     // forward: t in [0,m-1]; backward: [m,Tb-1]
    const int te = Tb - 1;
    const int maxch = T / CH - 1;

    int nit, cL = 0, c0 = 0;
    if (!BWD) {
        nit = (m + CH - 1) / CH;
    } else if (m > te) {                 // Tb==1: no backward steps
        nit = 0;
    } else {
        cL = te / CH; c0 = m / CH; nit = cL - c0 + 1;
    }

    auto chunk_of = [&](int i) {
        const int c = BWD ? (cL - i) : i;
        return imin(imax(c, 0), maxch);
    };

    // ---- LDS flag init (all 4 waves) ----
    for (int x = tid; x < MAXF; x += 64 * (NPROD + 1)) ready[x] = 0;
    if (tid == 0) *donec = 0;
    __syncthreads();

    // =================== producer waves ===================
    if (tid >= 64) {
        const int p = (tid >> 6) - 1;    // 0..2
        const int4 l4 = *reinterpret_cast<const int4*>(tgt + (size_t)b * L + lane * 4);
        const int c4[4] = {l4.x, l4.y, l4.z, l4.w};
        int lab[4];
#pragma unroll
        for (int k = 0; k < 4; ++k)
            lab[k] = (lane * 4 + k < U) ? (c4[k] & 127) : BLANK;

        double sb = 0.0;
        for (int j = p; j < nit; j += NPROD) {
            if (j >= NSLOT) {            // wait: slot (j&7) free (chunk j-8 consumed)
                while (__hip_atomic_load(donec, __ATOMIC_ACQUIRE,
                                         __HIP_MEMORY_SCOPE_WORKGROUP) < j - (NSLOT - 1))
                    __builtin_amdgcn_s_sleep(1);
            }
            const int c = chunk_of(j);
            float* slot = &gring[j & (NSLOT - 1)][0][0];
            const float* rowp = lp + ((size_t)(c * CH) * B + b) * CCH;
#pragma unroll 4
            for (int r = 0; r < CH; ++r) {
                const float* rp = rowp + (size_t)r * B * CCH;
                const float lpbv = rp[BLANK];
                float4 g;
                g.x = __expf(rp[lab[0]] - lpbv);   // pos>=U -> expf(0)=1 exactly
                g.y = __expf(rp[lab[1]] - lpbv);
                g.z = __expf(rp[lab[2]] - lpbv);
                g.w = __expf(rp[lab[3]] - lpbv);
                *reinterpret_cast<float4*>(slot + r * 256 + lane * 4) = g;
                const int t = c * CH + r;
                const bool valid = BWD ? (t >= m && t <= te) : (t < m);
                if (valid) sb += (double)lpbv;     // uniform across lanes
            }
            __hip_atomic_store(&ready[j], 1, __ATOMIC_RELEASE,
                               __HIP_MEMORY_SCOPE_WORKGROUP);  // g-writes drained first
        }
        if (lane == 0) {
            double* o = dout + (size_t)(BWD ? B + b : b) * DSTR;
            o[517 + p] = sb;             // per-producer fixed-order partial sum
        }
        return;
    }

    // =================== consumer wave (proven math, dedicated SIMD) ========
    double skipm[4];
    if (!BWD) {
        const int4 l4 = *reinterpret_cast<const int4*>(tgt + (size_t)b * L + lane * 4);
        const int labs[4] = {l4.x, l4.y, l4.z, l4.w};
        const int prevlast = __shfl_up(labs[3], 1);
#pragma unroll
        for (int k = 0; k < 4; ++k) {
            const int pos = lane * 4 + k;
            const int e = (pos < U) ? labs[k] : BLANK;
            int ep = (k == 0) ? ((pos >= 1) ? prevlast : BLANK) : labs[k - 1];
            ep = (pos >= 1 && pos - 1 < U) ? ep : BLANK;
            skipm[k] = (e != BLANK && e != ep) ? 1.0 : 0.0;
        }
    } else {
        const int4 l4 = *reinterpret_cast<const int4*>(tgt + (size_t)b * L + (63 - lane) * 4);
        const int labs[4] = {l4.x, l4.y, l4.z, l4.w};     // pos (63-lane)*4 + 0..3
        const int prevfirst = __shfl_up(labs[0], 1);      // lane-1's first label
#pragma unroll
        for (int k = 0; k < 4; ++k) {
            const int pos = 255 - lane * 4 - k;
            const int mylab = labs[3 - k];
            const int nxt = (k == 0) ? prevfirst : labs[4 - k];
            skipm[k] = ((pos + 1) < U && nxt != mylab) ? 1.0 : 0.0;
        }
    }

    double a[8];
#pragma unroll
    for (int j = 0; j < 8; ++j) a[j] = 0.0;
    double a512 = 0.0;    // fwd: s=512 shadow (lane63); bwd: sigma=512 (s=0) shadow
    int logz = 0;

    float4 R[CH];
    const int rdlane = (BWD ? (63 - lane) : lane) * 4;

    auto poll = [&](int i) {
        while (__hip_atomic_load(&ready[i], __ATOMIC_ACQUIRE,
                                 __HIP_MEMORY_SCOPE_WORKGROUP) == 0)
            __builtin_amdgcn_s_sleep(1);
    };

    auto c_load = [&](int i) {
        const float* sp = &gring[i & (NSLOT - 1)][0][0] + rdlane;
#pragma unroll
        for (int r = 0; r < CH; ++r)
            R[r] = *reinterpret_cast<const float4*>(sp + r * 256);
    };

    auto step = [&](const float4 gf) {
        const double g0 = (double)gf.x, g1 = (double)gf.y,
                     g2 = (double)gf.z, g3 = (double)gf.w;
        const double am1 = dpp_shr1_f64(a[7]);   // state[base-1] (lane0 -> 0)
        a512 += a[7];                            // pre-update a[7]
        const double n0 = a[0] + am1;
        const double n1 = (a[1] + a[0] + skipm[0] * am1) * g0;
        const double n2 = a[2] + a[1];
        const double n3 = (a[3] + a[2] + skipm[1] * a[1]) * g1;
        const double n4 = a[4] + a[3];
        const double n5 = (a[5] + a[4] + skipm[2] * a[3]) * g2;
        const double n6 = a[6] + a[5];
        const double n7 = (a[7] + a[6] + skipm[3] * a[5]) * g3;
        a[0] = n0; a[1] = n1; a[2] = n2; a[3] = n3;
        a[4] = n4; a[5] = n5; a[6] = n6; a[7] = n7;
    };

    auto rescale = [&]() {
        double mx = fmax(fmax(fmax(a[0], a[1]), fmax(a[2], a[3])),
                         fmax(fmax(a[4], a[5]), fmax(a[6], a[7])));
        int v = __double2hiint(mx);              // nonneg doubles: hi-word order = fp order
        int t;
        t = __builtin_amdgcn_update_dpp(0, v, 0x111, 0xF, 0xF, true); v = imax(v, t);
        t = __builtin_amdgcn_update_dpp(0, v, 0x112, 0xF, 0xF, true); v = imax(v, t);
        t = __builtin_amdgcn_update_dpp(0, v, 0x114, 0xF, 0xF, true); v = imax(v, t);
        t = __builtin_amdgcn_update_dpp(0, v, 0x118, 0xF, 0xF, true); v = imax(v, t);
        const int m0 = __builtin_amdgcn_readlane(v, 15);
        const int m1 = __builtin_amdgcn_readlane(v, 31);
        const int m2 = __builtin_amdgcn_readlane(v, 47);
        const int m3 = __builtin_amdgcn_readlane(v, 63);
        const int mb = imax(imax(m0, m1), imax(m2, m3));
        const int e11 = (mb >> 20) & 0x7FF;
        if (e11 > 0) {
            const double sc = __hiloint2double((2046 - e11) << 20, 0);  // 2^(1023-e11)
#pragma unroll
            for (int j = 0; j < 8; ++j) a[j] *= sc;
            a512 *= sc;
            logz += e11 - 1023;
        }
    };

    auto gswap = [](float4 v) { return make_float4(v.w, v.z, v.y, v.x); };
    auto initB = [&](float4 Rr) {                // delta_{Tb-1}
        const float4 g = gswap(Rr);
        const float gv[4] = {g.x, g.y, g.z, g.w};
#pragma unroll
        for (int j = 0; j < 8; ++j) {
            const int sig = 8 * lane + j;
            if ((j & 1) == 0) a[j] = (sig == 512 - 2 * U) ? 1.0 : 0.0;
            else              a[j] = (sig == 513 - 2 * U) ? (double)gv[(j - 1) >> 1] : 0.0;
        }
        a512 = (U == 0) ? 1.0 : 0.0;
    };

    auto consume = [&](int c) {
        if (!BWD) {
            const int t0 = c * CH;
            if (c == 0) {
                if (lane == 0) { a[0] = 1.0; a[1] = (double)R[0].x; }   // alpha_0
#pragma unroll
                for (int r = 1; r < CH; ++r) if (r < m) step(R[r]);
            } else if (t0 + CH <= m) {
#pragma unroll
                for (int r = 0; r < CH; ++r) step(R[r]);                // fast path
            } else {
#pragma unroll
                for (int r = 0; r < CH; ++r) if (t0 + r < m) step(R[r]);
            }
        } else {
            const int t0 = c * CH;
            if (t0 >= m && t0 + CH - 1 < te) {
#pragma unroll
                for (int r = CH - 1; r >= 0; --r) step(gswap(R[r]));    // fast path
            } else {
#pragma unroll
                for (int r = CH - 1; r >= 0; --r) {
                    const int t = t0 + r;
                    if (t > te || t < m) continue;
                    if (t == te) initB(R[r]); else step(gswap(R[r]));
                }
            }
        }
    };

    if (nit > 0) { poll(0); c_load(0); }
    for (int i = 0; i < nit; ++i) {
        consume(chunk_of(i));
        __hip_atomic_store(donec, i + 1, __ATOMIC_RELEASE,
                           __HIP_MEMORY_SCOPE_WORKGROUP);   // slot (i&7) reusable
        if (i + 1 < nit) { poll(i + 1); c_load(i + 1); }
        if ((i & 1) || (i == nit - 1)) rescale();           // every 32 steps, exact pow-2
    }
    if (BWD && nit == 0) {                // Tb==1: virtual terminal indicator
#pragma unroll
        for (int j = 0; j < 8; ++j) {
            const int sig = 8 * lane + j;
            a[j] = (((j & 1) == 0) && sig == 512 - 2 * U) ? 1.0 : 0.0;
        }
        a512 = (U == 0) ? 1.0 : 0.0;
    }

    // ---- epilogue: write s-indexed state + meta ----
    double* o = dout + (size_t)(BWD ? B + b : b) * DSTR;
#pragma unroll
    for (int j = 0; j < 8; ++j) {
        const int idx = BWD ? (512 - (8 * lane + j)) : (8 * lane + j);
        o[idx] = a[j];
    }
    if (lane == 63) o[BWD ? 0 : 512] = a512;
    if (lane == 0) {
        o[513] = 0.0; o[514] = 0.0; o[515] = 0.0;    // zero pad (combine reads s+1,s+2)
        o[516] = (double)logz;
    }
}

__global__ __launch_bounds__(64 * (NPROD + 1), 1)
void ctc_scan2(const float* __restrict__ lp, const int* __restrict__ ilen,
               const int* __restrict__ tgt, const int* __restrict__ tlen,
               double* __restrict__ dout, int T, int B, int L)
{
    __shared__ float gring[NSLOT][CH][256];   // 128 KB g-value ring
    __shared__ int   ready[MAXF];
    __shared__ int   donec;
    const int bid = blockIdx.x;
    if (bid < B) scan_dir<0>(lp, ilen, tgt, tlen, dout, T, B, L, bid, gring, ready, &donec);
    else         scan_dir<1>(lp, ilen, tgt, tlen, dout, T, B, L, bid - B, gring, ready, &donec);
}

// ---------------- pass 2: combine fwd/bwd halves ----------------
__global__ __launch_bounds__(64)
void ctc_combine(const double* __restrict__ dout,
                 const int* __restrict__ tgt,
                 const int* __restrict__ tlen,
                 float* __restrict__ perb, int B, int L)
{
    const int b = blockIdx.x;
    const int lane = threadIdx.x;
    int U = tlen[b]; if (U < 0) U = 0; if (U > L) U = L;

    const double* af = dout + (size_t)b * DSTR;
    const double* db = dout + (size_t)(B + b) * DSTR;

    const int4 l4 = *reinterpret_cast<const int4*>(tgt + (size_t)b * L + lane * 4);
    const int labs[4] = {l4.x, l4.y, l4.z, l4.w};
    const int nextfirst = __shfl_down(labs[0], 1);   // pos 4*lane+4

    double dd[10];
#pragma unroll
    for (int i = 0; i < 10; ++i) dd[i] = db[8 * lane + i];   // max idx 513 (zero pad)
    double av[8];
#pragma unroll
    for (int j = 0; j < 8; ++j) av[j] = af[8 * lane + j];

    double p = 0.0;
#pragma unroll
    for (int j = 0; j < 8; ++j) {
        if ((j & 1) == 0) {
            p += av[j] * (dd[j] + dd[j + 1]);
        } else {
            const int k = (j - 1) >> 1;
            const int pos = 4 * lane + k;
            const int nxt = (k < 3) ? labs[k + 1] : nextfirst;
            const double sk = ((pos + 1) < U && nxt != labs[k]) ? 1.0 : 0.0;
            p += av[j] * (dd[j] + dd[j + 1] + sk * dd[j + 2]);
        }
    }
    if (lane == 63) p += af[512] * db[512];
#pragma unroll
    for (int off = 32; off >= 1; off >>= 1) p += __shfl_xor(p, off);

    if (lane == 0) {
        const double zF = af[516], sF = af[517] + af[518] + af[519];
        const double zB = db[516], sB = db[517] + db[518] + db[519];
        const double ll = log(p) + sF + sB + (zF + zB) * 0.6931471805599453;
        perb[b] = (float)(-ll);
    }
}

// ---------------- fallback: proven round-3 single-kernel path ----------------
constexpr int FCH = 8;
constexpr int ROWD = 128;

__global__ __launch_bounds__(64, 1)
void ctc_fwd(const float* __restrict__ lp,
             const int* __restrict__ ilen,
             const int* __restrict__ tgt,
             const int* __restrict__ tlen,
             float* __restrict__ perb,
             int T, int B, int L)
{
    const int b = blockIdx.x;
    const int lane = threadIdx.x;
    int Tb = ilen[b]; if (Tb < 1) Tb = 1; if (Tb > T) Tb = T;
    int U  = tlen[b]; if (U < 0) U = 0;   if (U > L) U = L;

    __shared__ double pbuf[2][FCH][ROWD];
    __shared__ double afin[2 * 256 + 2];

    const int4 lab4 = *reinterpret_cast<const int4*>(tgt + (size_t)b * L + lane * 4);
    const int labs[4] = {lab4.x, lab4.y, lab4.z, lab4.w};
    const int prevlast = __shfl_up(labs[3], 1);
    int ext[4];
    double skipm[4];
#pragma unroll
    for (int k = 0; k < 4; ++k) {
        const int pos = lane * 4 + k;
        ext[k] = (pos < U) ? labs[k] : BLANK;
        const int prev = (k == 0) ? ((pos >= 1) ? prevlast : BLANK) : labs[k - 1];
        const int eprev = (pos >= 1 && pos - 1 < U) ? prev : BLANK;
        skipm[k] = (ext[k] != BLANK && ext[k] != eprev) ? 1.0 : 0.0;
    }

    const float* base = lp + (size_t)b * CCH;
    const size_t rowstride = (size_t)B * CCH;

    float2 rA[FCH], rB[FCH];
    double sblank = 0.0;
    int logz = 0;
    double a[8];
    double a512 = 0.0;
    double G[FCH][4];

    auto issue = [&](float2* r, int chunk) {
#pragma unroll
        for (int i = 0; i < FCH; ++i) {
            int t = chunk * FCH + i;
            t = (t < T) ? t : (T - 1);
            r[i] = *reinterpret_cast<const float2*>(base + (size_t)t * rowstride + 2 * lane);
        }
    };

    auto stage = [&](const float2* r, int buf, int chunk) {
#pragma unroll
        for (int i = 0; i < FCH; ++i) {
            const float2 v = r[i];
            const float lpb = __int_as_float(
                __builtin_amdgcn_readfirstlane(__float_as_int(v.y)));
            const int t = chunk * FCH + i;
            if (t < Tb) sblank += (double)lpb;
            double2 p;
            p.x = (double)__expf(v.x - lpb);
            p.y = (double)__expf(v.y - lpb);
            *reinterpret_cast<double2*>(&pbuf[buf][i][2 * lane]) = p;
        }
    };

    auto gather = [&](int buf) {
#pragma unroll
        for (int r = 0; r < FCH; ++r)
#pragma unroll
            for (int k = 0; k < 4; ++k)
                G[r][k] = pbuf[buf][r][ext[k]];
    };

    auto step = [&](const double* g) {
        const double am1 = dpp_shr1_f64(a[7]);
        a512 += a[7];
        const double n0 = a[0] + am1;
        const double n1 = (a[1] + a[0] + skipm[0] * am1) * g[0];
        const double n2 = a[2] + a[1];
        const double n3 = (a[3] + a[2] + skipm[1] * a[1]) * g[1];
        const double n4 = a[4] + a[3];
        const double n5 = (a[5] + a[4] + skipm[2] * a[3]) * g[2];
        const double n6 = a[6] + a[5];
        const double n7 = (a[7] + a[6] + skipm[3] * a[5]) * g[3];
        a[0] = n0; a[1] = n1; a[2] = n2; a[3] = n3;
        a[4] = n4; a[5] = n5; a[6] = n6; a[7] = n7;
    };

    auto rescale = [&]() {
        double m = fmax(fmax(fmax(a[0], a[1]), fmax(a[2], a[3])),
                        fmax(fmax(a[4], a[5]), fmax(a[6], a[7])));
        int v = __double2hiint(m);
        int t;
        t = __builtin_amdgcn_update_dpp(0, v, 0x111, 0xF, 0xF, true); v = imax(v, t);
        t = __builtin_amdgcn_update_dpp(0, v, 0x112, 0xF, 0xF, true); v = imax(v, t);
        t = __builtin_amdgcn_update_dpp(0, v, 0x114, 0xF, 0xF, true); v = imax(v, t);
        t = __builtin_amdgcn_update_dpp(0, v, 0x118, 0xF, 0xF, true); v = imax(v, t);
        const int m0 = __builtin_amdgcn_readlane(v, 15);
        const int m1 = __builtin_amdgcn_readlane(v, 31);
        const int m2 = __builtin_amdgcn_readlane(v, 47);
        const int m3 = __builtin_amdgcn_readlane(v, 63);
        const int mb = imax(imax(m0, m1), imax(m2, m3));
        const int e11 = (mb >> 20) & 0x7FF;
        if (e11 > 0) {
            const double sc = __hiloint2double((2046 - e11) << 20, 0);
#pragma unroll
            for (int j = 0; j < 8; ++j) a[j] *= sc;
            a512 *= sc;
            logz += e11 - 1023;
        }
    };

    issue(rA, 0);
    issue(rB, 1);
    stage(rA, 0, 0);
    issue(rA, 2);
#pragma unroll
    for (int j = 0; j < 8; ++j) a[j] = 0.0;

    const int nch = (Tb + FCH - 1) / FCH;

    for (int c = 0; c < nch; ++c) {
        const int buf = c & 1;
        gather(buf);
        if (c + 1 < nch) {
            if ((c + 1) & 1) { stage(rB, 1, c + 1); issue(rB, c + 3); }
            else             { stage(rA, 0, c + 1); issue(rA, c + 3); }
        }
        const int t0 = c * FCH;
        if (c == 0) {
            if (lane == 0) { a[0] = 1.0; a[1] = G[0][0]; }
#pragma unroll
            for (int r = 1; r < FCH; ++r) if (r < Tb) step(G[r]);
        } else if (t0 + FCH <= Tb) {
#pragma unroll
            for (int r = 0; r < FCH; ++r) step(G[r]);
        } else {
#pragma unroll
            for (int r = 0; r < FCH; ++r) if (t0 + r < Tb) step(G[r]);
        }
        if ((c & 1) || (c == nch - 1)) rescale();
    }

#pragma unroll
    for (int j = 0; j < 8; ++j) afin[lane * 8 + j] = a[j];
    if (lane == 63) afin[512] = a512;
    __syncthreads();
    if (lane == 0) {
        const int i1 = 2 * U;
        int i2 = 2 * U - 1; if (i2 < 0) i2 = 0;
        const double ssum = afin[i1] + afin[i2];
        const double ll = log(ssum) + sblank + (double)logz * 0.6931471805599453;
        perb[b] = (float)(-ll);
    }
}

__global__ void reduce_sum(const float* __restrict__ perb, float* __restrict__ out, int B)
{
    const int lane = threadIdx.x;
    double v = 0.0;
    for (int i = lane; i < B; i += 64) v += (double)perb[i];
#pragma unroll
    for (int off = 32; off >= 1; off >>= 1) v += __shfl_xor(v, off);
    if (lane == 0) out[0] = (float)v;
}

} // namespace

extern "C" void kernel_launch(void* const* d_in, const int* in_sizes, int n_in,
                              void* d_out, int out_size, void* d_ws, size_t ws_size,
                              hipStream_t stream)
{
    const float* lp  = (const float*)d_in[0];   // [T,B,C] log-softmax, f32
    const int* ilen  = (const int*)d_in[1];     // [B]
    const int* tgt   = (const int*)d_in[2];     // [B,L]
    const int* tlen  = (const int*)d_in[3];     // [B]

    const int B = in_sizes[1];
    const int L = in_sizes[2] / B;
    const int T = in_sizes[0] / (B * CCH);

    const size_t dbytes = (size_t)2 * B * DSTR * sizeof(double);
    const size_t need   = dbytes + (size_t)B * sizeof(float);

    if (ws_size >= need && L == 256 && (T % CH) == 0) {
        double* dout = (double*)d_ws;
        float*  perb = (float*)((char*)d_ws + dbytes);
        ctc_scan2<<<2 * B, 64 * (NPROD + 1), 0, stream>>>(lp, ilen, tgt, tlen, dout, T, B, L);
        ctc_combine<<<B, 64, 0, stream>>>(dout, tgt, tlen, perb, B, L);
        reduce_sum<<<1, 64, 0, stream>>>(perb, (float*)d_out, B);
    } else {
        float* perb = (float*)d_ws;
        ctc_fwd<<<B, 64, 0, stream>>>(lp, ilen, tgt, tlen, perb, T, B, L);
        reduce_sum<<<1, 64, 0, stream>>>(perb, (float*)d_out, B);
    }
}

// Round 20
// 73.714 us; speedup vs baseline: 1.3077x; 1.0002x over previous
//
#include <hip/hip_runtime.h>
#include <math.h>

namespace {

constexpr int CCH = 128;   // classes
constexpr int BLANK = 1;
constexpr int CH = 16;     // scan steps per chunk
constexpr int NSLOT = 8;   // LDS g-ring slots (128 KB)
constexpr int NPROD = 3;   // producer waves per block (4 waves total = 1/SIMD)
constexpr int MAXF = 128;  // ready-flag capacity (nit <= 64)
constexpr int DSTR = 524;  // f64 stride per (b,dir) result record

__device__ __forceinline__ int imax(int a, int b) { return a > b ? a : b; }
__device__ __forceinline__ int imin(int a, int b) { return a < b ? a : b; }

// lane i <- lane i-1 (lane 0 <- 0.0), pure VALU (DPP wave_shr:1)
__device__ __forceinline__ double dpp_shr1_f64(double x) {
    int lo = __double2loint(x), hi = __double2hiint(x);
    lo = __builtin_amdgcn_update_dpp(0, lo, 0x138, 0xF, 0xF, true);
    hi = __builtin_amdgcn_update_dpp(0, hi, 0x138, 0xF, 0xF, true);
    return __hiloint2double(hi, lo);
}

// ---------------- fused pass: 3 producer waves + 1 consumer wave ------------
// BWD uses mirrored states sigma = 512 - s, making its step identical to FWD's.
template<int BWD>
__device__ __forceinline__ void scan_dir(const float* __restrict__ lp,
                                         const int* __restrict__ ilen,
                                         const int* __restrict__ tgt,
                                         const int* __restrict__ tlen,
                                         double* __restrict__ dout,
                                         int T, int B, int L, int b,
                                         float (*gring)[CH][256],
                                         int* __restrict__ ready,
                                         int* __restrict__ donec)
{
    const int tid  = threadIdx.x;
    const int lane = tid & 63;
    int Tb = ilen[b]; if (Tb < 1) Tb = 1; if (Tb > T) Tb = T;
    int U  = tlen[b]; if (U < 0) U = 0;   if (U > L) U = L;
    const int m  = imax(1, Tb >> 1);     // forward: t in [0,m-1]; backward: [m,Tb-1]
    const int te = Tb - 1;
    const int maxch = T / CH - 1;

    int nit, cL = 0, c0 = 0;
    if (!BWD) {
        nit = (m + CH - 1) / CH;
    } else if (m > te) {                 // Tb==1: no backward steps
        nit = 0;
    } else {
        cL = te / CH; c0 = m / CH; nit = cL - c0 + 1;
    }

    auto chunk_of = [&](int i) {
        const int c = BWD ? (cL - i) : i;
        return imin(imax(c, 0), maxch);
    };

    // ---- LDS flag init (all 4 waves) ----
    for (int x = tid; x < MAXF; x += 64 * (NPROD + 1)) ready[x] = 0;
    if (tid == 0) *donec = 0;
    __syncthreads();

    // =================== producer waves ===================
    if (tid >= 64) {
        const int p = (tid >> 6) - 1;    // 0..2
        const int4 l4 = *reinterpret_cast<const int4*>(tgt + (size_t)b * L + lane * 4);
        const int c4[4] = {l4.x, l4.y, l4.z, l4.w};
        int lab[4];
#pragma unroll
        for (int k = 0; k < 4; ++k)
            lab[k] = (lane * 4 + k < U) ? (c4[k] & 127) : BLANK;

        double sb = 0.0;
        for (int j = p; j < nit; j += NPROD) {
            if (j >= NSLOT) {            // wait: slot (j&7) free (chunk j-8 consumed)
                while (__hip_atomic_load(donec, __ATOMIC_ACQUIRE,
                                         __HIP_MEMORY_SCOPE_WORKGROUP) < j - (NSLOT - 1))
                    __builtin_amdgcn_s_sleep(1);
            }
            const int c = chunk_of(j);
            float* slot = &gring[j & (NSLOT - 1)][0][0];
            const float* rowp = lp + ((size_t)(c * CH) * B + b) * CCH;
#pragma unroll 4
            for (int r = 0; r < CH; ++r) {
                const float* rp = rowp + (size_t)r * B * CCH;
                const float lpbv = rp[BLANK];
                float4 g;
                g.x = __expf(rp[lab[0]] - lpbv);   // pos>=U -> expf(0)=1 exactly
                g.y = __expf(rp[lab[1]] - lpbv);
                g.z = __expf(rp[lab[2]] - lpbv);
                g.w = __expf(rp[lab[3]] - lpbv);
                *reinterpret_cast<float4*>(slot + r * 256 + lane * 4) = g;
                const int t = c * CH + r;
                const bool valid = BWD ? (t >= m && t <= te) : (t < m);
                if (valid) sb += (double)lpbv;     // uniform across lanes
            }
            __hip_atomic_store(&ready[j], 1, __ATOMIC_RELEASE,
                               __HIP_MEMORY_SCOPE_WORKGROUP);  // g-writes drained first
        }
        if (lane == 0) {
            double* o = dout + (size_t)(BWD ? B + b : b) * DSTR;
            o[517 + p] = sb;             // per-producer fixed-order partial sum
        }
        return;
    }

    // =================== consumer wave (proven math, dedicated SIMD) ========
    double skipm[4];
    if (!BWD) {
        const int4 l4 = *reinterpret_cast<const int4*>(tgt + (size_t)b * L + lane * 4);
        const int labs[4] = {l4.x, l4.y, l4.z, l4.w};
        const int prevlast = __shfl_up(labs[3], 1);
#pragma unroll
        for (int k = 0; k < 4; ++k) {
            const int pos = lane * 4 + k;
            const int e = (pos < U) ? labs[k] : BLANK;
            int ep = (k == 0) ? ((pos >= 1) ? prevlast : BLANK) : labs[k - 1];
            ep = (pos >= 1 && pos - 1 < U) ? ep : BLANK;
            skipm[k] = (e != BLANK && e != ep) ? 1.0 : 0.0;
        }
    } else {
        const int4 l4 = *reinterpret_cast<const int4*>(tgt + (size_t)b * L + (63 - lane) * 4);
        const int labs[4] = {l4.x, l4.y, l4.z, l4.w};     // pos (63-lane)*4 + 0..3
        const int prevfirst = __shfl_up(labs[0], 1);      // lane-1's first label
#pragma unroll
        for (int k = 0; k < 4; ++k) {
            const int pos = 255 - lane * 4 - k;
            const int mylab = labs[3 - k];
            const int nxt = (k == 0) ? prevfirst : labs[4 - k];
            skipm[k] = ((pos + 1) < U && nxt != mylab) ? 1.0 : 0.0;
        }
    }

    double a[8];
#pragma unroll
    for (int j = 0; j < 8; ++j) a[j] = 0.0;
    double a512 = 0.0;    // fwd: s=512 shadow (lane63); bwd: sigma=512 (s=0) shadow
    int logz = 0;

    float4 R[CH];
    const int rdlane = (BWD ? (63 - lane) : lane) * 4;

    auto poll = [&](int i) {
        while (__hip_atomic_load(&ready[i], __ATOMIC_ACQUIRE,
                                 __HIP_MEMORY_SCOPE_WORKGROUP) == 0)
            __builtin_amdgcn_s_sleep(1);
    };

    auto c_load = [&](int i) {
        const float* sp = &gring[i & (NSLOT - 1)][0][0] + rdlane;
#pragma unroll
        for (int r = 0; r < CH; ++r)
            R[r] = *reinterpret_cast<const float4*>(sp + r * 256);
    };

    auto step = [&](const float4 gf) {
        const double g0 = (double)gf.x, g1 = (double)gf.y,
                     g2 = (double)gf.z, g3 = (double)gf.w;
        const double am1 = dpp_shr1_f64(a[7]);   // state[base-1] (lane0 -> 0)
        a512 += a[7];                            // pre-update a[7]
        const double n0 = a[0] + am1;
        const double n1 = (a[1] + a[0] + skipm[0] * am1) * g0;
        const double n2 = a[2] + a[1];
        const double n3 = (a[3] + a[2] + skipm[1] * a[1]) * g1;
        const double n4 = a[4] + a[3];
        const double n5 = (a[5] + a[4] + skipm[2] * a[3]) * g2;
        const double n6 = a[6] + a[5];
        const double n7 = (a[7] + a[6] + skipm[3] * a[5]) * g3;
        a[0] = n0; a[1] = n1; a[2] = n2; a[3] = n3;
        a[4] = n4; a[5] = n5; a[6] = n6; a[7] = n7;
    };

    auto rescale = [&]() {
        double mx = fmax(fmax(fmax(a[0], a[1]), fmax(a[2], a[3])),
                         fmax(fmax(a[4], a[5]), fmax(a[6], a[7])));
        int v = __double2hiint(mx);              // nonneg doubles: hi-word order = fp order
        int t;
        t = __builtin_amdgcn_update_dpp(0, v, 0x111, 0xF, 0xF, true); v = imax(v, t);
        t = __builtin_amdgcn_update_dpp(0, v, 0x112, 0xF, 0xF, true); v = imax(v, t);
        t = __builtin_amdgcn_update_dpp(0, v, 0x114, 0xF, 0xF, true); v = imax(v, t);
        t = __builtin_amdgcn_update_dpp(0, v, 0x118, 0xF, 0xF, true); v = imax(v, t);
        const int m0 = __builtin_amdgcn_readlane(v, 15);
        const int m1 = __builtin_amdgcn_readlane(v, 31);
        const int m2 = __builtin_amdgcn_readlane(v, 47);
        const int m3 = __builtin_amdgcn_readlane(v, 63);
        const int mb = imax(imax(m0, m1), imax(m2, m3));
        const int e11 = (mb >> 20) & 0x7FF;
        if (e11 > 0) {
            const double sc = __hiloint2double((2046 - e11) << 20, 0);  // 2^(1023-e11)
#pragma unroll
            for (int j = 0; j < 8; ++j) a[j] *= sc;
            a512 *= sc;
            logz += e11 - 1023;
        }
    };

    auto gswap = [](float4 v) { return make_float4(v.w, v.z, v.y, v.x); };
    auto initB = [&](float4 Rr) {                // delta_{Tb-1}
        const float4 g = gswap(Rr);
        const float gv[4] = {g.x, g.y, g.z, g.w};
#pragma unroll
        for (int j = 0; j < 8; ++j) {
            const int sig = 8 * lane + j;
            if ((j & 1) == 0) a[j] = (sig == 512 - 2 * U) ? 1.0 : 0.0;
            else              a[j] = (sig == 513 - 2 * U) ? (double)gv[(j - 1) >> 1] : 0.0;
        }
        a512 = (U == 0) ? 1.0 : 0.0;
    };

    auto consume = [&](int c) {
        if (!BWD) {
            const int t0 = c * CH;
            if (c == 0) {
                if (lane == 0) { a[0] = 1.0; a[1] = (double)R[0].x; }   // alpha_0
#pragma unroll
                for (int r = 1; r < CH; ++r) if (r < m) step(R[r]);
            } else if (t0 + CH <= m) {
#pragma unroll
                for (int r = 0; r < CH; ++r) step(R[r]);                // fast path
            } else {
#pragma unroll
                for (int r = 0; r < CH; ++r) if (t0 + r < m) step(R[r]);
            }
        } else {
            const int t0 = c * CH;
            if (t0 >= m && t0 + CH - 1 < te) {
#pragma unroll
                for (int r = CH - 1; r >= 0; --r) step(gswap(R[r]));    // fast path
            } else {
#pragma unroll
                for (int r = CH - 1; r >= 0; --r) {
                    const int t = t0 + r;
                    if (t > te || t < m) continue;
                    if (t == te) initB(R[r]); else step(gswap(R[r]));
                }
            }
        }
    };

    if (nit > 0) { poll(0); c_load(0); }
    for (int i = 0; i < nit; ++i) {
        consume(chunk_of(i));
        __hip_atomic_store(donec, i + 1, __ATOMIC_RELEASE,
                           __HIP_MEMORY_SCOPE_WORKGROUP);   // slot (i&7) reusable
        if (i + 1 < nit) { poll(i + 1); c_load(i + 1); }
        if ((i & 1) || (i == nit - 1)) rescale();           // every 32 steps, exact pow-2
    }
    if (BWD && nit == 0) {                // Tb==1: virtual terminal indicator
#pragma unroll
        for (int j = 0; j < 8; ++j) {
            const int sig = 8 * lane + j;
            a[j] = (((j & 1) == 0) && sig == 512 - 2 * U) ? 1.0 : 0.0;
        }
        a512 = (U == 0) ? 1.0 : 0.0;
    }

    // ---- epilogue: write s-indexed state + meta ----
    double* o = dout + (size_t)(BWD ? B + b : b) * DSTR;
#pragma unroll
    for (int j = 0; j < 8; ++j) {
        const int idx = BWD ? (512 - (8 * lane + j)) : (8 * lane + j);
        o[idx] = a[j];
    }
    if (lane == 63) o[BWD ? 0 : 512] = a512;
    if (lane == 0) {
        o[513] = 0.0; o[514] = 0.0; o[515] = 0.0;    // zero pad (combine reads s+1,s+2)
        o[516] = (double)logz;
    }
}

__global__ __launch_bounds__(64 * (NPROD + 1), 1)
void ctc_scan2(const float* __restrict__ lp, const int* __restrict__ ilen,
               const int* __restrict__ tgt, const int* __restrict__ tlen,
               double* __restrict__ dout, int T, int B, int L)
{
    __shared__ float gring[NSLOT][CH][256];   // 128 KB g-value ring
    __shared__ int   ready[MAXF];
    __shared__ int   donec;
    const int bid = blockIdx.x;
    if (bid < B) scan_dir<0>(lp, ilen, tgt, tlen, dout, T, B, L, bid, gring, ready, &donec);
    else         scan_dir<1>(lp, ilen, tgt, tlen, dout, T, B, L, bid - B, gring, ready, &donec);
}

// ---------------- pass 2: combine fwd/bwd halves ----------------
__global__ __launch_bounds__(64)
void ctc_combine(const double* __restrict__ dout,
                 const int* __restrict__ tgt,
                 const int* __restrict__ tlen,
                 float* __restrict__ perb, int B, int L)
{
    const int b = blockIdx.x;
    const int lane = threadIdx.x;
    int U = tlen[b]; if (U < 0) U = 0; if (U > L) U = L;

    const double* af = dout + (size_t)b * DSTR;
    const double* db = dout + (size_t)(B + b) * DSTR;

    const int4 l4 = *reinterpret_cast<const int4*>(tgt + (size_t)b * L + lane * 4);
    const int labs[4] = {l4.x, l4.y, l4.z, l4.w};
    const int nextfirst = __shfl_down(labs[0], 1);   // pos 4*lane+4

    double dd[10];
#pragma unroll
    for (int i = 0; i < 10; ++i) dd[i] = db[8 * lane + i];   // max idx 513 (zero pad)
    double av[8];
#pragma unroll
    for (int j = 0; j < 8; ++j) av[j] = af[8 * lane + j];

    double p = 0.0;
#pragma unroll
    for (int j = 0; j < 8; ++j) {
        if ((j & 1) == 0) {
            p += av[j] * (dd[j] + dd[j + 1]);
        } else {
            const int k = (j - 1) >> 1;
            const int pos = 4 * lane + k;
            const int nxt = (k < 3) ? labs[k + 1] : nextfirst;
            const double sk = ((pos + 1) < U && nxt != labs[k]) ? 1.0 : 0.0;
            p += av[j] * (dd[j] + dd[j + 1] + sk * dd[j + 2]);
        }
    }
    if (lane == 63) p += af[512] * db[512];
#pragma unroll
    for (int off = 32; off >= 1; off >>= 1) p += __shfl_xor(p, off);

    if (lane == 0) {
        const double zF = af[516], sF = af[517] + af[518] + af[519];
        const double zB = db[516], sB = db[517] + db[518] + db[519];
        const double ll = log(p) + sF + sB + (zF + zB) * 0.6931471805599453;
        perb[b] = (float)(-ll);
    }
}

// ---------------- fallback: proven round-3 single-kernel path ----------------
constexpr int FCH = 8;
constexpr int ROWD = 128;

__global__ __launch_bounds__(64, 1)
void ctc_fwd(const float* __restrict__ lp,
             const int* __restrict__ ilen,
             const int* __restrict__ tgt,
             const int* __restrict__ tlen,
             float* __restrict__ perb,
             int T, int B, int L)
{
    const int b = blockIdx.x;
    const int lane = threadIdx.x;
    int Tb = ilen[b]; if (Tb < 1) Tb = 1; if (Tb > T) Tb = T;
    int U  = tlen[b]; if (U < 0) U = 0;   if (U > L) U = L;

    __shared__ double pbuf[2][FCH][ROWD];
    __shared__ double afin[2 * 256 + 2];

    const int4 lab4 = *reinterpret_cast<const int4*>(tgt + (size_t)b * L + lane * 4);
    const int labs[4] = {lab4.x, lab4.y, lab4.z, lab4.w};
    const int prevlast = __shfl_up(labs[3], 1);
    int ext[4];
    double skipm[4];
#pragma unroll
    for (int k = 0; k < 4; ++k) {
        const int pos = lane * 4 + k;
        ext[k] = (pos < U) ? labs[k] : BLANK;
        const int prev = (k == 0) ? ((pos >= 1) ? prevlast : BLANK) : labs[k - 1];
        const int eprev = (pos >= 1 && pos - 1 < U) ? prev : BLANK;
        skipm[k] = (ext[k] != BLANK && ext[k] != eprev) ? 1.0 : 0.0;
    }

    const float* base = lp + (size_t)b * CCH;
    const size_t rowstride = (size_t)B * CCH;

    float2 rA[FCH], rB[FCH];
    double sblank = 0.0;
    int logz = 0;
    double a[8];
    double a512 = 0.0;
    double G[FCH][4];

    auto issue = [&](float2* r, int chunk) {
#pragma unroll
        for (int i = 0; i < FCH; ++i) {
            int t = chunk * FCH + i;
            t = (t < T) ? t : (T - 1);
            r[i] = *reinterpret_cast<const float2*>(base + (size_t)t * rowstride + 2 * lane);
        }
    };

    auto stage = [&](const float2* r, int buf, int chunk) {
#pragma unroll
        for (int i = 0; i < FCH; ++i) {
            const float2 v = r[i];
            const float lpb = __int_as_float(
                __builtin_amdgcn_readfirstlane(__float_as_int(v.y)));
            const int t = chunk * FCH + i;
            if (t < Tb) sblank += (double)lpb;
            double2 p;
            p.x = (double)__expf(v.x - lpb);
            p.y = (double)__expf(v.y - lpb);
            *reinterpret_cast<double2*>(&pbuf[buf][i][2 * lane]) = p;
        }
    };

    auto gather = [&](int buf) {
#pragma unroll
        for (int r = 0; r < FCH; ++r)
#pragma unroll
            for (int k = 0; k < 4; ++k)
                G[r][k] = pbuf[buf][r][ext[k]];
    };

    auto step = [&](const double* g) {
        const double am1 = dpp_shr1_f64(a[7]);
        a512 += a[7];
        const double n0 = a[0] + am1;
        const double n1 = (a[1] + a[0] + skipm[0] * am1) * g[0];
        const double n2 = a[2] + a[1];
        const double n3 = (a[3] + a[2] + skipm[1] * a[1]) * g[1];
        const double n4 = a[4] + a[3];
        const double n5 = (a[5] + a[4] + skipm[2] * a[3]) * g[2];
        const double n6 = a[6] + a[5];
        const double n7 = (a[7] + a[6] + skipm[3] * a[5]) * g[3];
        a[0] = n0; a[1] = n1; a[2] = n2; a[3] = n3;
        a[4] = n4; a[5] = n5; a[6] = n6; a[7] = n7;
    };

    auto rescale = [&]() {
        double m = fmax(fmax(fmax(a[0], a[1]), fmax(a[2], a[3])),
                        fmax(fmax(a[4], a[5]), fmax(a[6], a[7])));
        int v = __double2hiint(m);
        int t;
        t = __builtin_amdgcn_update_dpp(0, v, 0x111, 0xF, 0xF, true); v = imax(v, t);
        t = __builtin_amdgcn_update_dpp(0, v, 0x112, 0xF, 0xF, true); v = imax(v, t);
        t = __builtin_amdgcn_update_dpp(0, v, 0x114, 0xF, 0xF, true); v = imax(v, t);
        t = __builtin_amdgcn_update_dpp(0, v, 0x118, 0xF, 0xF, true); v = imax(v, t);
        const int m0 = __builtin_amdgcn_readlane(v, 15);
        const int m1 = __builtin_amdgcn_readlane(v, 31);
        const int m2 = __builtin_amdgcn_readlane(v, 47);
        const int m3 = __builtin_amdgcn_readlane(v, 63);
        const int mb = imax(imax(m0, m1), imax(m2, m3));
        const int e11 = (mb >> 20) & 0x7FF;
        if (e11 > 0) {
            const double sc = __hiloint2double((2046 - e11) << 20, 0);
#pragma unroll
            for (int j = 0; j < 8; ++j) a[j] *= sc;
            a512 *= sc;
            logz += e11 - 1023;
        }
    };

    issue(rA, 0);
    issue(rB, 1);
    stage(rA, 0, 0);
    issue(rA, 2);
#pragma unroll
    for (int j = 0; j < 8; ++j) a[j] = 0.0;

    const int nch = (Tb + FCH - 1) / FCH;

    for (int c = 0; c < nch; ++c) {
        const int buf = c & 1;
        gather(buf);
        if (c + 1 < nch) {
            if ((c + 1) & 1) { stage(rB, 1, c + 1); issue(rB, c + 3); }
            else             { stage(rA, 0, c + 1); issue(rA, c + 3); }
        }
        const int t0 = c * FCH;
        if (c == 0) {
            if (lane == 0) { a[0] = 1.0; a[1] = G[0][0]; }
#pragma unroll
            for (int r = 1; r < FCH; ++r) if (r < Tb) step(G[r]);
        } else if (t0 + FCH <= Tb) {
#pragma unroll
            for (int r = 0; r < FCH; ++r) step(G[r]);
        } else {
#pragma unroll
            for (int r = 0; r < FCH; ++r) if (t0 + r < Tb) step(G[r]);
        }
        if ((c & 1) || (c == nch - 1)) rescale();
    }

#pragma unroll
    for (int j = 0; j < 8; ++j) afin[lane * 8 + j] = a[j];
    if (lane == 63) afin[512] = a512;
    __syncthreads();
    if (lane == 0) {
        const int i1 = 2 * U;
        int i2 = 2 * U - 1; if (i2 < 0) i2 = 0;
        const double ssum = afin[i1] + afin[i2];
        const double ll = log(ssum) + sblank + (double)logz * 0.6931471805599453;
        perb[b] = (float)(-ll);
    }
}

__global__ void reduce_sum(const float* __restrict__ perb, float* __restrict__ out, int B)
{
    const int lane = threadIdx.x;
    double v = 0.0;
    for (int i = lane; i < B; i += 64) v += (double)perb[i];
#pragma unroll
    for (int off = 32; off >= 1; off >>= 1) v += __shfl_xor(v, off);
    if (lane == 0) out[0] = (float)v;
}

} // namespace

extern "C" void kernel_launch(void* const* d_in, const int* in_sizes, int n_in,
                              void* d_out, int out_size, void* d_ws, size_t ws_size,
                              hipStream_t stream)
{
    const float* lp  = (const float*)d_in[0];   // [T,B,C] log-softmax, f32
    const int* ilen  = (const int*)d_in[1];     // [B]
    const int* tgt   = (const int*)d_in[2];     // [B,L]
    const int* tlen  = (const int*)d_in[3];     // [B]

    const int B = in_sizes[1];
    const int L = in_sizes[2] / B;
    const int T = in_sizes[0] / (B * CCH);

    const size_t dbytes = (size_t)2 * B * DSTR * sizeof(double);
    const size_t need   = dbytes + (size_t)B * sizeof(float);

    if (ws_size >= need && L == 256 && (T % CH) == 0) {
        double* dout = (double*)d_ws;
        float*  perb = (float*)((char*)d_ws + dbytes);
        ctc_scan2<<<2 * B, 64 * (NPROD + 1), 0, stream>>>(lp, ilen, tgt, tlen, dout, T, B, L);
        ctc_combine<<<B, 64, 0, stream>>>(dout, tgt, tlen, perb, B, L);
        reduce_sum<<<1, 64, 0, stream>>>(perb, (float*)d_out, B);
    } else {
        float* perb = (float*)d_ws;
        ctc_fwd<<<B, 64, 0, stream>>>(lp, ilen, tgt, tlen, perb, T, B, L);
        reduce_sum<<<1, 64, 0, stream>>>(perb, (float*)d_out, B);
    }
}